// Round 3
// baseline (88.822 us; speedup 1.0000x reference)
//
#include <hip/hip_runtime.h>
#include <stdint.h>

// MHABlock: b=8, c=128, heads=8, d=16, spatial 32x32 (p=1024).
// Softmax over last spatial axis only -> independent 32-key blocks.
// R16: R13 verbatim (grid 512, 32 x-blocks/wave, no LDS) with ONLY the
// register-diet change from R14/R15:
//  - stage2 packs P = e*rs to bf16 immediately (pm_lo/pm_hi, 8 regs) instead
//    of carrying e_prev[16] + rs_prev;
//  - stage3 C-chains PV into a single f32x16 pacc (no pv0/pv1 transients,
//    no fmaf fold).
// Algebraically identical to R13's deferred fold; ~40 fewer live+transient
// VGPRs -> natural occupancy 2->3 waves/SIMD. No launch-bounds forcing.
// Pipeline: stage1 issues S(x+1); stage2 exp/sum/rcp/pack for x; stage3 PV
// for x-1. Distance-2 K prefetch, 3-deep V rotation.
// S^T = K*Q^T via mfma_32x32x16 (K=16 exact); V stored y-bits-2,3-swapped so
// PV B-frags are sequential in-lane packs of the exp'd scores.

typedef __bf16 bf16x8 __attribute__((ext_vector_type(8)));
typedef float f32x16 __attribute__((ext_vector_type(16)));

// ws layout (units: shorts): Q | K | V, 1M shorts each
#define QOFF  0u
#define KOFF  (1u << 20)
#define VOFF  (2u << 20)

static __device__ __forceinline__ unsigned short f2bf(float f) {
  union { float f; uint32_t u; } v; v.f = f;
  uint32_t r = (v.u + 0x7FFFu + ((v.u >> 16) & 1u)) >> 16;  // RNE
  return (unsigned short)r;
}
static __device__ __forceinline__ uint32_t pkrne(float lo, float hi) {
  return (uint32_t)f2bf(lo) | ((uint32_t)f2bf(hi) << 16);
}
static __device__ __forceinline__ uint32_t pktrunc(float lo, float hi) {
  return (__builtin_bit_cast(uint32_t, hi) & 0xffff0000u) |
         (__builtin_bit_cast(uint32_t, lo) >> 16);
}
static __device__ __forceinline__ float fexp2(float x) {
  float r;
  asm("v_exp_f32 %0, %1" : "=v"(r) : "v"(x));  // non-volatile: schedulable
  return r;
}
static __device__ __forceinline__ f32x16 zero16() {
  f32x16 z;
#pragma unroll
  for (int i = 0; i < 16; ++i) z[i] = 0.f;
  return z;
}
// swap bits 2,3 (V spatial permutation within each 32-block)
static __device__ __forceinline__ int perm23(int p) {
  return (p & ~12) | ((p & 4) << 1) | ((p & 8) >> 1);
}
static __device__ __forceinline__ bf16x8 pack8(float f0, float f1, float f2,
                                               float f3, float f4, float f5,
                                               float f6, float f7) {
  uint4 u = make_uint4(pkrne(f0, f1), pkrne(f2, f3), pkrne(f4, f5), pkrne(f6, f7));
  return __builtin_bit_cast(bf16x8, u);
}

// ---------------------------------------------------------------------------
// proj (MFMA, fused fp32->bf16): D[out 32][p 32], K=128.
// grid = b*48 + mat*16 + ptile (384), block = 256.  (identical to R9..R15)
// ---------------------------------------------------------------------------
__global__ __launch_bounds__(256) void proj_kernel(
    const float* __restrict__ x, const float* __restrict__ wq,
    const float* __restrict__ wk, const float* __restrict__ wv,
    unsigned short* __restrict__ ws) {
  int bid = blockIdx.x;
  int ptile = bid & 15;
  int mat = (bid >> 4) % 3;
  int b = bid / 48;
  int t = threadIdx.x;
  int wave = t >> 6, lane = t & 63;
  int h = lane >> 5, c = lane & 31;
  int out0 = wave * 32;

  const float* w = (mat == 0) ? wq : ((mat == 1) ? wk : wv);
  const float* wrow = w + (size_t)(out0 + c) * 128 + h * 8;      // A: W[out0+c][k]
  const float* xcol = x + (size_t)b * 131072 + ptile * 64 + c;   // B: x[ch][p]

  f32x16 acc0 = zero16(), acc1 = zero16();
#pragma unroll
  for (int kt = 0; kt < 8; ++kt) {
    int ch0 = kt * 16 + h * 8;
    float4 wa = *(const float4*)(wrow + kt * 16);
    float4 wb4 = *(const float4*)(wrow + kt * 16 + 4);
    float xb0[8], xb1[8];
#pragma unroll
    for (int j = 0; j < 8; ++j) {
      xb0[j] = xcol[(size_t)(ch0 + j) * 1024];
      xb1[j] = xcol[(size_t)(ch0 + j) * 1024 + 32];
    }
    bf16x8 af = pack8(wa.x, wa.y, wa.z, wa.w, wb4.x, wb4.y, wb4.z, wb4.w);
    bf16x8 b0 = pack8(xb0[0], xb0[1], xb0[2], xb0[3], xb0[4], xb0[5], xb0[6], xb0[7]);
    bf16x8 b1 = pack8(xb1[0], xb1[1], xb1[2], xb1[3], xb1[4], xb1[5], xb1[6], xb1[7]);
    acc0 = __builtin_amdgcn_mfma_f32_32x32x16_bf16(af, b0, acc0, 0, 0, 0);
    acc1 = __builtin_amdgcn_mfma_f32_32x32x16_bf16(af, b1, acc1, 0, 0, 0);
  }

  if (mat < 2) {
    // Q: fold softmax scale d^-0.5 * log2(e) (attn uses exp2)
    float s = (mat == 0) ? 0.36067376022224085f : 1.0f;
    unsigned short* dst = ws + ((mat == 0) ? QOFF : KOFF);
#pragma unroll
    for (int nt = 0; nt < 2; ++nt) {
      f32x16 a = nt ? acc1 : acc0;
      int p = ptile * 64 + nt * 32 + c;
#pragma unroll
      for (int rg = 0; rg < 4; ++rg) {
        int bn = b * 8 + wave * 2 + (rg >> 1);
        int dbase = ((rg & 1) ? 8 : 0) + 4 * h;
        uint32_t lo = pkrne(a[rg * 4 + 0] * s, a[rg * 4 + 1] * s);
        uint32_t hi = pkrne(a[rg * 4 + 2] * s, a[rg * 4 + 3] * s);
        *(uint2*)(dst + (size_t)bn * 16384 + (size_t)p * 16 + dbase) =
            make_uint2(lo, hi);
      }
    }
  } else {
#pragma unroll
    for (int nt = 0; nt < 2; ++nt) {
      f32x16 a = nt ? acc1 : acc0;
      int p = ptile * 64 + nt * 32 + c;
      int pp = perm23(p);
#pragma unroll
      for (int r = 0; r < 16; ++r) {
        int moff = (r & 3) + 8 * (r >> 2) + 4 * h;
        int head = (out0 + moff) >> 4;
        int d = moff & 15;
        ws[VOFF + (size_t)(b * 8 + head) * 16384 + (size_t)d * 1024 + pp] =
            f2bf(a[r]);
      }
    }
  }
}

// ---------------------------------------------------------------------------
// attn: grid = bn*8+qc (512), block = 256 (4 waves), 32 q/wave, 32 x-blocks.
// No LDS, no barriers, direct stores. 3-stage pipeline; rs pre-folded into P
// (pktrunc pack), PV C-chained into one f32x16 accumulator.
// ---------------------------------------------------------------------------
__global__ __launch_bounds__(256) void attn_kernel(
    const unsigned short* __restrict__ ws, float* __restrict__ out) {
  int bid = blockIdx.x;
  int qc = bid & 7, bn = bid >> 3;
  const unsigned short* Qg = ws + QOFF + (size_t)bn * 16384;
  const unsigned short* Kg = ws + KOFF + (size_t)bn * 16384;
  const unsigned short* Vg = ws + VOFF + (size_t)bn * 16384;

  int t = threadIdx.x;
  int wave = t >> 6, lane = t & 63;
  int h = lane >> 5, c = lane & 31;
  int q0 = qc * 128 + wave * 32;

  // Q B-frag: B[k=d=8h+j][n=q=c], K=16 exact
  bf16x8 qb = __builtin_bit_cast(
      bf16x8, *(const uint4*)(Qg + (size_t)(q0 + c) * 16 + h * 8));

  // K A-frag: lane reads K[x*32 + c][8h..8h+7]  (coalesced 16B/lane)
  const unsigned short* kbase = Kg + (size_t)c * 16 + h * 8;
  // V A-frag: lane reads V'[c&15][x*32 + 8h..]
  const unsigned short* vbase = Vg + (size_t)(c & 15) * 1024 + h * 8;

  f32x16 pacc = zero16();

  // ---- prologue ----
  // V slots: va_p = frags for x-1 ; v_c = raw V(x) ; v_n = raw V(x+1)
  bf16x8 va0_p = __builtin_bit_cast(bf16x8, *(const uint4*)(vbase));
  bf16x8 va1_p = __builtin_bit_cast(bf16x8, *(const uint4*)(vbase + 16));
  uint4 v0_c = *(const uint4*)(vbase + 32);        // V(1)
  uint4 v1_c = *(const uint4*)(vbase + 48);
  uint4 v0_n = *(const uint4*)(vbase + 64);        // V(2)
  uint4 v1_n = *(const uint4*)(vbase + 80);

  uint4 kf0 = *(const uint4*)(kbase);
  f32x16 sv0 = __builtin_amdgcn_mfma_f32_32x32x16_bf16(
      __builtin_bit_cast(bf16x8, kf0), qb, zero16(), 0, 0, 0);  // S(0)
  uint4 kf1 = *(const uint4*)(kbase + 512);
  f32x16 sv_cur = __builtin_amdgcn_mfma_f32_32x32x16_bf16(
      __builtin_bit_cast(bf16x8, kf1), qb, zero16(), 0, 0, 0);  // S(1)

  // stage2(0): exp/sum/rcp, fold rs, pack to bf16 (pktrunc)
  bf16x8 pm_lo, pm_hi;
  {
    float e[16];
#pragma unroll
    for (int r = 0; r < 16; ++r) e[r] = fexp2(sv0[r]);
    float s0 = (e[0] + e[1]) + (e[2] + e[3]);
    float s1 = (e[4] + e[5]) + (e[6] + e[7]);
    float s2 = (e[8] + e[9]) + (e[10] + e[11]);
    float s3 = (e[12] + e[13]) + (e[14] + e[15]);
    float sum = (s0 + s1) + (s2 + s3);
    sum += __shfl_xor(sum, 32);
    float rs = __builtin_amdgcn_rcpf(sum);
    uint32_t pm[8];
#pragma unroll
    for (int j = 0; j < 8; ++j)
      pm[j] = pktrunc(e[2 * j] * rs, e[2 * j + 1] * rs);
    pm_lo = __builtin_bit_cast(bf16x8, make_uint4(pm[0], pm[1], pm[2], pm[3]));
    pm_hi = __builtin_bit_cast(bf16x8, make_uint4(pm[4], pm[5], pm[6], pm[7]));
  }

  uint4 kf_a = *(const uint4*)(kbase + 2 * 512);   // K(2)
  uint4 kf_b = *(const uint4*)(kbase + 3 * 512);   // K(3)

  // ---- main loop: x = 1..31 ----
#pragma unroll 2
  for (int x = 1; x < 32; ++x) {
    // stage1: issue S(x+1) (kf_a = K(x+1)); redundant clamp at x=31
    f32x16 sv_next = __builtin_amdgcn_mfma_f32_32x32x16_bf16(
        __builtin_bit_cast(bf16x8, kf_a), qb, zero16(), 0, 0, 0);
    kf_a = kf_b;
    int x3 = (x > 28) ? 31 : (x + 3);
    kf_b = *(const uint4*)(kbase + (size_t)x3 * 512);

    // stage3 for x-1: PV, C-chained (rs already folded into pm)
    pacc = __builtin_amdgcn_mfma_f32_32x32x16_bf16(va0_p, pm_lo, pacc, 0, 0, 0);
    pacc = __builtin_amdgcn_mfma_f32_32x32x16_bf16(va1_p, pm_hi, pacc, 0, 0, 0);

    // stage2 for x: exp/sum/rcp on sv_cur (computed at iter x-1), pack
    {
      float e[16];
#pragma unroll
      for (int r = 0; r < 16; ++r) e[r] = fexp2(sv_cur[r]);
      float t0 = (e[0] + e[1]) + (e[2] + e[3]);
      float t1 = (e[4] + e[5]) + (e[6] + e[7]);
      float t2 = (e[8] + e[9]) + (e[10] + e[11]);
      float t3 = (e[12] + e[13]) + (e[14] + e[15]);
      float su = (t0 + t1) + (t2 + t3);
      su += __shfl_xor(su, 32);
      float rs = __builtin_amdgcn_rcpf(su);
      uint32_t pm[8];
#pragma unroll
      for (int j = 0; j < 8; ++j)
        pm[j] = pktrunc(e[2 * j] * rs, e[2 * j + 1] * rs);
      pm_lo = __builtin_bit_cast(bf16x8, make_uint4(pm[0], pm[1], pm[2], pm[3]));
      pm_hi = __builtin_bit_cast(bf16x8, make_uint4(pm[4], pm[5], pm[6], pm[7]));
    }

    // rotate V: va_p <- V(x); v_c <- V(x+1); load V(x+2) into v_n
    va0_p = __builtin_bit_cast(bf16x8, v0_c);
    va1_p = __builtin_bit_cast(bf16x8, v1_c);
    v0_c = v0_n; v1_c = v1_n;
    int x2 = (x > 29) ? 31 : (x + 2);
    v0_n = *(const uint4*)(vbase + x2 * 32);
    v1_n = *(const uint4*)(vbase + x2 * 32 + 16);

    sv_cur = sv_next;
  }

  // ---- epilogue: stage3 for x=31 ----
  pacc = __builtin_amdgcn_mfma_f32_32x32x16_bf16(va0_p, pm_lo, pacc, 0, 0, 0);
  pacc = __builtin_amdgcn_mfma_f32_32x32x16_bf16(va1_p, pm_hi, pacc, 0, 0, 0);

  // Epilogue: D rows 0..15 valid (rows 16..31 are duplicate-V garbage)
#pragma unroll
  for (int r = 0; r < 8; ++r) {
    int d = (r & 3) + 8 * (r >> 2) + 4 * h;
    out[(size_t)(bn * 16 + d) * 1024 + q0 + c] = pacc[r];
  }
}

// ---------------------------------------------------------------------------
extern "C" void kernel_launch(void* const* d_in, const int* in_sizes, int n_in,
                              void* d_out, int out_size, void* d_ws, size_t ws_size,
                              hipStream_t stream) {
  const float* x  = (const float*)d_in[0];
  const float* wq = (const float*)d_in[1];
  const float* wk = (const float*)d_in[2];
  const float* wv = (const float*)d_in[3];
  unsigned short* ws = (unsigned short*)d_ws;
  float* out = (float*)d_out;

  proj_kernel<<<dim3(384), dim3(256), 0, stream>>>(x, wq, wk, wv, ws);
  attn_kernel<<<dim3(512), dim3(256), 0, stream>>>(ws, out);
}